// Round 4
// baseline (57.602 us; speedup 1.0000x reference)
//
#include <hip/hip_runtime.h>
#include <hip/hip_fp16.h>

typedef _Float16 half8 __attribute__((ext_vector_type(8)));
typedef _Float16 half4v __attribute__((ext_vector_type(4)));
typedef _Float16 half2v __attribute__((ext_vector_type(2)));
typedef float f32x4 __attribute__((ext_vector_type(4)));

#define N_INNER 511
#define NPAD 512
#define FEAT 1024
#define BATCH 16384
#define NCLS 100
#define NCLSPAD 112

#define AS1 __attribute__((address_space(1)))
#define AS3 __attribute__((address_space(3)))

// ---------------- prep: W -> Wh f16 [512][1024] (row 511 zero); L -> LT f16 [112][512] ----------------
__global__ void k_prep(const float* __restrict__ W, const float* __restrict__ L,
                       _Float16* __restrict__ Wh, _Float16* __restrict__ LT) {
  const int i = blockIdx.x * 256 + threadIdx.x;

  if (i < 65536) {  // Wh: 524,288 elems, 8 per thread
    const int off = i * 8;
    const int row = off >> 10;
    half8 h;
    if (row < N_INNER) {
      const float4 a = *(const float4*)(W + off);
      const float4 b = *(const float4*)(W + off + 4);
      h[0] = (_Float16)a.x; h[1] = (_Float16)a.y; h[2] = (_Float16)a.z; h[3] = (_Float16)a.w;
      h[4] = (_Float16)b.x; h[5] = (_Float16)b.y; h[6] = (_Float16)b.z; h[7] = (_Float16)b.w;
    } else {
      h = (half8)(_Float16)0.f;
    }
    *(half8*)(Wh + off) = h;
  }

  if (i < NCLSPAD * NPAD) {  // LT transpose-pad
    const int n = i >> 9, k = i & 511;
    LT[i] = (n < NCLS) ? (_Float16)L[(size_t)k * NCLS + n] : (_Float16)0.f;
  }
}

// ---------------- GEMM1: gates = sigmoid(x @ Wh^T + b), heap-layout f16 out [16384][512] ----------------
// 128x128 tile, BK=32, 512 threads (8 waves 2x4). Double-buffered LDS, 1 barrier/iter.
// A (f32 x): reg-staged (load-early / cvt+ds_write-late), padded LDS stride 40.
// B (f16 Wh): global_load_lds width 16, linear LDS [128][32].
#define LDA 40

__global__ __launch_bounds__(512, 2) void k_gemm1(
    const float* __restrict__ x, const _Float16* __restrict__ Wh,
    const float* __restrict__ bias, _Float16* __restrict__ gates) {
  __shared__ _Float16 lA[2][128 * LDA];
  __shared__ _Float16 lB[2][128 * 32];

  const int t = threadIdx.x;
  const int lane = t & 63;
  const int w = t >> 6;
  const int wm = w >> 2, wn = w & 3;  // 2 x 4 waves

  // XCD swizzle: the 4 bn-siblings of each bm land on the same XCD
  const int bid = blockIdx.x;
  const int xcd = bid & 7, jj = bid >> 3;
  const int bm = (jj >> 2) * 8 + xcd;  // 0..127
  const int bn = jj & 3;               // 0..3

  // staging task: thread t owns (row t>>2 in 0..127, 8-elem seg t&3)
  const int sr = t >> 2, ss = t & 3;
  const float*    pa = x  + (size_t)(bm * 128 + sr) * FEAT + ss * 8;
  const _Float16* pb = Wh + (size_t)(bn * 128 + sr) * FEAT + ss * 8;
  const int aoff = sr * LDA + ss * 8;  // byte addr = sr*80 + ss*16 : 16B-aligned, banks balanced

  f32x4 acc[4][2] = {};
  float4 ra, rb;

  auto a_load = [&](int k0) {
    ra = *(const float4*)(pa + k0);
    rb = *(const float4*)(pa + k0 + 4);
  };
  auto a_write = [&](int B) {
    half8 h;
    h[0] = (_Float16)ra.x; h[1] = (_Float16)ra.y; h[2] = (_Float16)ra.z; h[3] = (_Float16)ra.w;
    h[4] = (_Float16)rb.x; h[5] = (_Float16)rb.y; h[6] = (_Float16)rb.z; h[7] = (_Float16)rb.w;
    *(half8*)&lA[B][aoff] = h;
  };
  auto b_stage = [&](int k0, int B) {
    // 512 threads x 16B = full 8KB tile; LDS dest = wave-uniform base + lane*16
    __builtin_amdgcn_global_load_lds((const AS1 void*)(pb + k0),
                                     (AS3 void*)((char*)&lB[B][0] + w * 1024), 16, 0, 0);
  };

  // prologue: fill buf 0
  a_load(0);
  b_stage(0, 0);
  a_write(0);
  __syncthreads();

  for (int kk = 0; kk < 32; ++kk) {
    const int cur = kk & 1;
    if (kk < 31) {
      a_load((kk + 1) * 32);        // issue early: latency hides under MFMA below
      b_stage((kk + 1) * 32, cur ^ 1);
    }

    half8 af[4], bf[2];
#pragma unroll
    for (int i = 0; i < 4; ++i)
      af[i] = *(const half8*)&lA[cur][(wm * 64 + i * 16 + (lane & 15)) * LDA + (lane >> 4) * 8];
#pragma unroll
    for (int j = 0; j < 2; ++j)
      bf[j] = *(const half8*)&lB[cur][(wn * 32 + j * 16 + (lane & 15)) * 32 + (lane >> 4) * 8];

#pragma unroll
    for (int i = 0; i < 4; ++i)
#pragma unroll
      for (int j = 0; j < 2; ++j)
        acc[i][j] = __builtin_amdgcn_mfma_f32_16x16x32_f16(af[i], bf[j], acc[i][j], 0, 0, 0);

    if (kk < 31) a_write(cur ^ 1);  // write late (after compute), other buffer
    __syncthreads();                 // drains vmcnt (B) + lgkm (A writes)
  }

  // epilogue: bias + sigmoid, store f16 to heap position (col+1)&511
#pragma unroll
  for (int j = 0; j < 2; ++j) {
    const int col = bn * 128 + wn * 32 + j * 16 + (lane & 15);
    const float bb = (col < N_INNER) ? bias[col] : 0.f;
    const int hpos = (col + 1) & 511;
#pragma unroll
    for (int i = 0; i < 4; ++i) {
      const int rowb = bm * 128 + wm * 64 + i * 16 + ((lane >> 4) << 2);
#pragma unroll
      for (int r = 0; r < 4; ++r) {
        float v = acc[i][j][r] + bb;
        v = 1.f / (1.f + __expf(-v));
        gates[(size_t)(rowb + r) * NPAD + hpos] = (_Float16)v;
      }
    }
  }
}

// ---------------- K2: tree expansion + GEMM2 (prob @ leaf_logits) ----------------
#define LPS 520

__global__ __launch_bounds__(512, 4) void k_tree(
    const _Float16* __restrict__ gates, const _Float16* __restrict__ LT,
    float* __restrict__ out) {
  __shared__ _Float16 lp[32 * LPS];

  const int t = threadIdx.x;
  const int rowl = t >> 4, sub = t & 15;
  const size_t grow = (size_t)blockIdx.x * 32 + rowl;
  const _Float16* g = gates + grow * NPAD;

  const float f0 = (float)g[1];
  const float f1 = (float)g[2 + (sub >> 3)];
  const float f2 = (float)g[4 + (sub >> 2)];
  const float f3 = (float)g[8 + (sub >> 1)];
  const _Float16 g4 = g[16 + sub];
  const half2v g5 = *(const half2v*)(g + 32 + 2 * sub);
  const half4v g6 = *(const half4v*)(g + 64 + 4 * sub);
  const half8 g7 = *(const half8*)(g + 128 + 8 * sub);
  const half8 g8a = *(const half8*)(g + 256 + 16 * sub);
  const half8 g8b = *(const half8*)(g + 256 + 16 * sub + 8);

  float p = ((sub & 8) ? f0 : 1.f - f0) * ((sub & 4) ? f1 : 1.f - f1) *
            ((sub & 2) ? f2 : 1.f - f2) * ((sub & 1) ? f3 : 1.f - f3);

  float arr[32];
  {
    const float gg = (float)g4;
    arr[1] = p * gg; arr[0] = p - p * gg;
  }
#pragma unroll
  for (int i = 1; i >= 0; --i) {
    const float gg = (float)g5[i];
    const float pp = arr[i];
    arr[2 * i + 1] = pp * gg; arr[2 * i] = pp - pp * gg;
  }
#pragma unroll
  for (int i = 3; i >= 0; --i) {
    const float gg = (float)g6[i];
    const float pp = arr[i];
    arr[2 * i + 1] = pp * gg; arr[2 * i] = pp - pp * gg;
  }
#pragma unroll
  for (int i = 7; i >= 0; --i) {
    const float gg = (float)g7[i];
    const float pp = arr[i];
    arr[2 * i + 1] = pp * gg; arr[2 * i] = pp - pp * gg;
  }
#pragma unroll
  for (int i = 15; i >= 0; --i) {
    const float gg = (i < 8) ? (float)g8a[i] : (float)g8b[i - 8];
    const float pp = arr[i];
    arr[2 * i + 1] = pp * gg; arr[2 * i] = pp - pp * gg;
  }

  const int lb = sub * 32;
#pragma unroll
  for (int i = 0; i < 32; i += 8) {
    half8 h;
#pragma unroll
    for (int jj = 0; jj < 8; ++jj) h[jj] = (_Float16)arr[i + jj];
    *(half8*)&lp[rowl * LPS + lb + i] = h;
  }
  __syncthreads();

  const int lane = t & 63, w = t >> 6;
  if (w < 7) {
    f32x4 acc[2] = {};
#pragma unroll
    for (int k0 = 0; k0 < 512; k0 += 32) {
      const int n = w * 16 + (lane & 15);
      const half8 b8 = *(const half8*)&LT[(size_t)n * NPAD + k0 + (lane >> 4) * 8];
#pragma unroll
      for (int mf = 0; mf < 2; ++mf) {
        const half8 a = *(const half8*)&lp[(mf * 16 + (lane & 15)) * LPS + k0 + (lane >> 4) * 8];
        acc[mf] = __builtin_amdgcn_mfma_f32_16x16x32_f16(a, b8, acc[mf], 0, 0, 0);
      }
    }

    const int col = w * 16 + (lane & 15);
    if (col < NCLS) {
#pragma unroll
      for (int mf = 0; mf < 2; ++mf) {
        const int rowb = blockIdx.x * 32 + mf * 16 + ((lane >> 4) << 2);
#pragma unroll
        for (int r = 0; r < 4; ++r)
          out[(size_t)(rowb + r) * NCLS + col] = acc[mf][r];
      }
    }
  }
}

extern "C" void kernel_launch(void* const* d_in, const int* in_sizes, int n_in,
                              void* d_out, int out_size, void* d_ws, size_t ws_size,
                              hipStream_t stream) {
  const float* x = (const float*)d_in[0];
  const float* W = (const float*)d_in[1];
  const float* b = (const float*)d_in[2];
  const float* L = (const float*)d_in[3];
  float* out = (float*)d_out;

  char* ws = (char*)d_ws;
  _Float16* Wh    = (_Float16*)ws;                 // 1 MB @ 0
  _Float16* LT    = (_Float16*)(ws + (1u << 20));  // 112 KB @ 1 MB
  _Float16* gates = (_Float16*)(ws + (2u << 20));  // 16 MB @ 2 MB

  k_prep<<<256, 256, 0, stream>>>(W, L, Wh, LT);
  k_gemm1<<<512, 512, 0, stream>>>(x, Wh, b, gates);
  k_tree<<<512, 512, 0, stream>>>(gates, LT, out);
}